// Round 4
// baseline (191.173 us; speedup 1.0000x reference)
//
#include <hip/hip_runtime.h>

#define BATCH 128
#define VIS   98
#define TOK   196
#define TOK2  392
#define ENC   1024
#define DEC   512
#define MSK   294   // 2*TOK - VIS

#define NXB 6272   // (B*V*ENC/4) float4s / 512 threads
#define NWB 256    // (DEC*ENC/4)  float4s / 512 threads

typedef __bf16 bf16x8 __attribute__((ext_vector_type(8)));
typedef float  f32x4  __attribute__((ext_vector_type(4)));

__device__ __forceinline__ unsigned short f2bf(float f) {
    union { float f; unsigned u; } c; c.f = f;
    unsigned u = c.u;
    return (unsigned short)((u + 0x7fffu + ((u >> 16) & 1u)) >> 16);
}

// async global -> LDS, 16 B per lane; LDS dest must be wave-uniform base + lane*16
__device__ __forceinline__ void g2lds16(const void* gptr, void* lptr) {
    __builtin_amdgcn_global_load_lds(
        (const __attribute__((address_space(1))) void*)gptr,
        (__attribute__((address_space(3))) void*)lptr, 16, 0, 0);
}

// One fused setup dispatch:
//   blocks [0, NXB)          : x  fp32 -> bf16
//   blocks [NXB, NXB+NWB)    : W  fp32 -> bf16
//   blocks [NXB+NWB, +BATCH) : build visibility map per batch row
__global__ __launch_bounds__(512) void setup(const float* __restrict__ x,
                                             const float* __restrict__ W,
                                             const int* __restrict__ mids,
                                             unsigned short* __restrict__ xb,
                                             unsigned short* __restrict__ wbm,
                                             int* __restrict__ visids,
                                             unsigned char* __restrict__ flags) {
    int bid = blockIdx.x, tid = threadIdx.x;
    if (bid < NXB + NWB) {
        const float* src = (bid < NXB) ? x : W;
        unsigned short* dst = (bid < NXB) ? xb : wbm;
        int i = (bid < NXB ? bid : bid - NXB) * 512 + tid;
        float4 f = ((const float4*)src)[i];
        ushort4 o;
        o.x = f2bf(f.x); o.y = f2bf(f.y); o.z = f2bf(f.z); o.w = f2bf(f.w);
        ((ushort4*)dst)[i] = o;
        return;
    }
    int b = bid - NXB - NWB;
    __shared__ unsigned char lf[TOK2];
    __shared__ int wtot[8];
    if (tid < TOK2) lf[tid] = 1;
    __syncthreads();
    if (tid < MSK) lf[mids[b * MSK + tid]] = 0;
    __syncthreads();
    int flag = (tid < TOK2) ? (int)lf[tid] : 0;
    unsigned long long bal = __ballot(flag != 0);
    int lane = tid & 63, wv = tid >> 6;
    int pre = __popcll(bal & ((1ull << lane) - 1ull));
    if (lane == 0) wtot[wv] = __popcll(bal);
    __syncthreads();
    int off = 0;
    for (int i = 0; i < wv; ++i) off += wtot[i];
    if (flag) visids[b * VIS + off + pre] = tid;   // stable: ascending token id
    if (tid < TOK2) flags[b * TOK2 + tid] = lf[tid];
}

// masked slots: out = mask_token + pos + view_embed
__global__ __launch_bounds__(256) void fill_masked(const unsigned char* __restrict__ flags,
                                                   const float* __restrict__ mask_token,
                                                   const float* __restrict__ pos,
                                                   const float* __restrict__ ve,
                                                   float* __restrict__ out) {
    int b = blockIdx.y;
    int g = blockIdx.x * 256 + threadIdx.x;   // over TOK2*128 float4 slots
    int t  = g >> 7;
    int d4 = g & 127;
    int tok = b * TOK2 + t;
    if (flags[tok]) return;                   // visible -> written by gemm_scatter
    float4 m = ((const float4*)mask_token)[d4];
    float4 p = ((const float4*)(pos + (size_t)t * DEC))[d4];
    float4 v = ((const float4*)(ve + (t >= TOK ? DEC : 0)))[d4];
    float4 r;
    r.x = m.x + p.x + v.x;
    r.y = m.y + p.y + v.y;
    r.z = m.z + p.z + v.z;
    r.w = m.w + p.w + v.w;
    ((float4*)(out + (size_t)tok * DEC))[d4] = r;
}

// xp = x @ W^T + bias, scattered to out[b, visids[b,v], :] (+pos +ve).
// 128x128 tile, BK=64, 256 thr (4 waves 2x2), global_load_lds staging, A and B both bf16.
// XOR chunk swizzle: row r stores logical chunk c at physical slot c ^ (r&7); fragment
// read of chunk (u*4+q) for row (..+l16) reads slot (u*4+q)^(l16&7).
// mfma_f32_16x16x32_bf16: A lane: row=l&15, k=(l>>4)*8+j ; B lane: col=l&15, same k;
// D lane: col=l&15, row=(l>>4)*4+reg   [m89-verified layout]
__global__ __launch_bounds__(256, 4) void gemm_scatter(
    const unsigned short* __restrict__ xb,   // (B*V, ENC) bf16 bits
    const unsigned short* __restrict__ wb,   // (DEC, ENC) bf16 bits
    const float* __restrict__ bias,
    const float* __restrict__ pos,
    const float* __restrict__ ve,
    const int* __restrict__ vis,             // (B*V) -> t
    float* __restrict__ out) {
    __shared__ unsigned short As[128 * 64];  // 16 KB
    __shared__ unsigned short Bs[128 * 64];  // 16 KB
    __shared__ int rowdst[128];
    __shared__ int rowt[128];

    int tid = threadIdx.x;
    int lane = tid & 63, w = tid >> 6;
    int l16 = lane & 15, q = lane >> 4;
    int wm = w & 1, wn = w >> 1;
    int m0 = blockIdx.y * 128, n0 = blockIdx.x * 128;

    if (tid < 128) {
        int gr = m0 + tid;
        int t = vis[gr];
        rowt[tid] = t;
        rowdst[tid] = (gr / VIS) * TOK2 + t;
    }

    // staging: thread -> row (tid>>3), chunk slot (tid&7); global chunk c = slot ^ (row&7)
    int c = (tid & 7) ^ ((tid >> 3) & 7);
    const unsigned short* gA = xb + (size_t)(m0 + (tid >> 3)) * ENC + c * 8;
    const unsigned short* gB = wb + (size_t)(n0 + (tid >> 3)) * ENC + c * 8;
    char* ldsA = (char*)As + tid * 16;
    char* ldsB = (char*)Bs + tid * 16;

    f32x4 acc[4][4];
    #pragma unroll
    for (int i = 0; i < 4; ++i)
        #pragma unroll
        for (int j = 0; j < 4; ++j)
            acc[i][j] = (f32x4){0.f, 0.f, 0.f, 0.f};

    for (int k0 = 0; k0 < ENC; k0 += 64) {
        __syncthreads();
        #pragma unroll
        for (int t = 0; t < 4; ++t)                  // A tile: 128 rows x 64 k bf16
            g2lds16(gA + (size_t)t * 32 * ENC + k0, ldsA + t * 4096);
        #pragma unroll
        for (int t = 0; t < 4; ++t)                  // B tile: 128 rows x 64 k bf16
            g2lds16(gB + (size_t)t * 32 * ENC + k0, ldsB + t * 4096);
        __syncthreads();

        #pragma unroll
        for (int u = 0; u < 2; ++u) {                // two k32 substeps
            int slot = ((u * 4 + q) ^ (l16 & 7)) * 16;
            bf16x8 bfrag[4], afrag[4];
            #pragma unroll
            for (int j = 0; j < 4; ++j)
                bfrag[j] = *(const bf16x8*)((const char*)Bs + (wn * 64 + j * 16 + l16) * 128 + slot);
            #pragma unroll
            for (int i = 0; i < 4; ++i)
                afrag[i] = *(const bf16x8*)((const char*)As + (wm * 64 + i * 16 + l16) * 128 + slot);
            #pragma unroll
            for (int i = 0; i < 4; ++i)
                #pragma unroll
                for (int j = 0; j < 4; ++j)
                    acc[i][j] = __builtin_amdgcn_mfma_f32_16x16x32_bf16(afrag[i], bfrag[j], acc[i][j], 0, 0, 0);
        }
    }

    // epilogue: +bias +pos +view_embed, scatter rows to out[b, t, :]
    #pragma unroll
    for (int j = 0; j < 4; ++j) {
        int gcol = n0 + wn * 64 + j * 16 + l16;
        float bc = bias[gcol];
        float v0 = ve[gcol];
        float v1 = ve[DEC + gcol];
        #pragma unroll
        for (int i = 0; i < 4; ++i) {
            #pragma unroll
            for (int r = 0; r < 4; ++r) {
                int rl = wm * 64 + i * 16 + q * 4 + r;
                int t = rowt[rl];
                float val = acc[i][j][r] + bc + pos[(size_t)t * DEC + gcol]
                          + (t >= TOK ? v1 : v0);
                out[(size_t)rowdst[rl] * DEC + gcol] = val;
            }
        }
    }
}

extern "C" void kernel_launch(void* const* d_in, const int* in_sizes, int n_in,
                              void* d_out, int out_size, void* d_ws, size_t ws_size,
                              hipStream_t stream) {
    (void)in_sizes; (void)n_in; (void)out_size; (void)ws_size;
    const float* x    = (const float*)d_in[0];
    const int*   mids = (const int*)d_in[1];
    const float* W    = (const float*)d_in[2];
    const float* bias = (const float*)d_in[3];
    const float* mt   = (const float*)d_in[4];
    const float* pos  = (const float*)d_in[5];
    const float* ve   = (const float*)d_in[6];
    float* out = (float*)d_out;

    // workspace: x bf16 (25.7 MB) + W bf16 (1 MB) + maps
    unsigned short* xb = (unsigned short*)d_ws;                      // B*V*ENC bf16
    unsigned short* wbm = xb + (size_t)BATCH * VIS * ENC;            // DEC*ENC bf16
    int* visids = (int*)(wbm + (size_t)DEC * ENC);                   // B*V int
    unsigned char* flags = (unsigned char*)(visids + BATCH * VIS);   // B*392 bytes

    hipLaunchKernelGGL(setup, dim3(NXB + NWB + BATCH), dim3(512), 0, stream,
                       x, W, mids, xb, wbm, visids, flags);
    hipLaunchKernelGGL(fill_masked, dim3(TOK2 * 128 / 256, BATCH), dim3(256), 0, stream,
                       flags, mt, pos, ve, out);
    hipLaunchKernelGGL(gemm_scatter, dim3(4, (BATCH * VIS) / 128), dim3(256), 0, stream,
                       xb, wbm, bias, pos, ve, visids, out);
}

// Round 5
// 183.517 us; speedup vs baseline: 1.0417x; 1.0417x over previous
//
#include <hip/hip_runtime.h>

#define BATCH 128
#define VIS   98
#define TOK   196
#define TOK2  392
#define ENC   1024
#define DEC   512
#define MSK   294   // 2*TOK - VIS

#define NXB 6272   // (B*V*ENC/4) float4s / 512 threads
#define NWB 256    // (DEC*ENC/4)  float4s / 512 threads

typedef __bf16 bf16x8 __attribute__((ext_vector_type(8)));
typedef float  f32x4  __attribute__((ext_vector_type(4)));

__device__ __forceinline__ unsigned short f2bf(float f) {
    union { float f; unsigned u; } c; c.f = f;
    unsigned u = c.u;
    return (unsigned short)((u + 0x7fffu + ((u >> 16) & 1u)) >> 16);
}

// async global -> LDS, 16 B per lane; LDS dest must be wave-uniform base + lane*16
__device__ __forceinline__ void g2lds16(const void* gptr, void* lptr) {
    __builtin_amdgcn_global_load_lds(
        (const __attribute__((address_space(1))) void*)gptr,
        (__attribute__((address_space(3))) void*)lptr, 16, 0, 0);
}

// One fused setup dispatch:
//   blocks [0, NXB)          : x  fp32 -> bf16
//   blocks [NXB, NXB+NWB)    : W  fp32 -> bf16
//   blocks [NXB+NWB, +BATCH) : build visibility map per batch row
__global__ __launch_bounds__(512) void setup(const float* __restrict__ x,
                                             const float* __restrict__ W,
                                             const int* __restrict__ mids,
                                             unsigned short* __restrict__ xb,
                                             unsigned short* __restrict__ wbm,
                                             int* __restrict__ visids,
                                             unsigned char* __restrict__ flags) {
    int bid = blockIdx.x, tid = threadIdx.x;
    if (bid < NXB + NWB) {
        const float* src = (bid < NXB) ? x : W;
        unsigned short* dst = (bid < NXB) ? xb : wbm;
        int i = (bid < NXB ? bid : bid - NXB) * 512 + tid;
        float4 f = ((const float4*)src)[i];
        ushort4 o;
        o.x = f2bf(f.x); o.y = f2bf(f.y); o.z = f2bf(f.z); o.w = f2bf(f.w);
        ((ushort4*)dst)[i] = o;
        return;
    }
    int b = bid - NXB - NWB;
    __shared__ unsigned char lf[TOK2];
    __shared__ int wtot[8];
    if (tid < TOK2) lf[tid] = 1;
    __syncthreads();
    if (tid < MSK) lf[mids[b * MSK + tid]] = 0;
    __syncthreads();
    int flag = (tid < TOK2) ? (int)lf[tid] : 0;
    unsigned long long bal = __ballot(flag != 0);
    int lane = tid & 63, wv = tid >> 6;
    int pre = __popcll(bal & ((1ull << lane) - 1ull));
    if (lane == 0) wtot[wv] = __popcll(bal);
    __syncthreads();
    int off = 0;
    for (int i = 0; i < wv; ++i) off += wtot[i];
    if (flag) visids[b * VIS + off + pre] = tid;   // stable: ascending token id
    if (tid < TOK2) flags[b * TOK2 + tid] = lf[tid];
}

// masked slots: out = mask_token + pos + view_embed
__global__ __launch_bounds__(256) void fill_masked(const unsigned char* __restrict__ flags,
                                                   const float* __restrict__ mask_token,
                                                   const float* __restrict__ pos,
                                                   const float* __restrict__ ve,
                                                   float* __restrict__ out) {
    int b = blockIdx.y;
    int g = blockIdx.x * 256 + threadIdx.x;   // over TOK2*128 float4 slots
    int t  = g >> 7;
    int d4 = g & 127;
    int tok = b * TOK2 + t;
    if (flags[tok]) return;                   // visible -> written by gemm_scatter
    float4 m = ((const float4*)mask_token)[d4];
    float4 p = ((const float4*)(pos + (size_t)t * DEC))[d4];
    float4 v = ((const float4*)(ve + (t >= TOK ? DEC : 0)))[d4];
    float4 r;
    r.x = m.x + p.x + v.x;
    r.y = m.y + p.y + v.y;
    r.z = m.z + p.z + v.z;
    r.w = m.w + p.w + v.w;
    ((float4*)(out + (size_t)tok * DEC))[d4] = r;
}

// xp = x @ W^T + bias, scattered to out[b, visids[b,v], :] (+pos +ve).
// 64m x 128n tile, BK=64, 256 thr (4 waves 2x2; wave = 32m x 64n, acc[2][4]).
// Grid (4, 196) = 784 blocks (~3/CU) for CU balance + inter-block latency hiding.
// global_load_lds staging, A and B bf16. XOR chunk swizzle: row r stores logical
// chunk c at slot c ^ (r&7); fragment read of chunk (u*4+q) reads slot (u*4+q)^(l16&7).
// mfma_f32_16x16x32_bf16: A lane: row=l&15, k=(l>>4)*8+j ; B lane: col=l&15, same k;
// D lane: col=l&15, row=(l>>4)*4+reg   [m89-verified layout]
__global__ __launch_bounds__(256, 4) void gemm_scatter(
    const unsigned short* __restrict__ xb,   // (B*V, ENC) bf16 bits
    const unsigned short* __restrict__ wb,   // (DEC, ENC) bf16 bits
    const float* __restrict__ bias,
    const float* __restrict__ pos,
    const float* __restrict__ ve,
    const int* __restrict__ vis,             // (B*V) -> t
    float* __restrict__ out) {
    __shared__ unsigned short As[64 * 64];   // 8 KB
    __shared__ unsigned short Bs[128 * 64];  // 16 KB
    __shared__ int rowdst[64];
    __shared__ int rowt[64];

    int tid = threadIdx.x;
    int lane = tid & 63, w = tid >> 6;
    int l16 = lane & 15, q = lane >> 4;
    int wm = w & 1, wn = w >> 1;
    int m0 = blockIdx.y * 64, n0 = blockIdx.x * 128;

    if (tid < 64) {
        int gr = m0 + tid;
        int t = vis[gr];
        rowt[tid] = t;
        rowdst[tid] = (gr / VIS) * TOK2 + t;
    }

    // staging: thread -> row (tid>>3), chunk slot (tid&7); global chunk c = slot ^ (row&7)
    int c = (tid & 7) ^ ((tid >> 3) & 7);
    const unsigned short* gA = xb + (size_t)(m0 + (tid >> 3)) * ENC + c * 8;
    const unsigned short* gB = wb + (size_t)(n0 + (tid >> 3)) * ENC + c * 8;
    char* ldsA = (char*)As + tid * 16;
    char* ldsB = (char*)Bs + tid * 16;

    f32x4 acc[2][4];
    #pragma unroll
    for (int i = 0; i < 2; ++i)
        #pragma unroll
        for (int j = 0; j < 4; ++j)
            acc[i][j] = (f32x4){0.f, 0.f, 0.f, 0.f};

    for (int k0 = 0; k0 < ENC; k0 += 64) {
        __syncthreads();
        #pragma unroll
        for (int t = 0; t < 2; ++t)                  // A tile: 64 rows x 64 k bf16
            g2lds16(gA + (size_t)t * 32 * ENC + k0, ldsA + t * 4096);
        #pragma unroll
        for (int t = 0; t < 4; ++t)                  // B tile: 128 rows x 64 k bf16
            g2lds16(gB + (size_t)t * 32 * ENC + k0, ldsB + t * 4096);
        __syncthreads();

        #pragma unroll
        for (int u = 0; u < 2; ++u) {                // two k32 substeps
            int slot = ((u * 4 + q) ^ (l16 & 7)) * 16;
            bf16x8 bfrag[4], afrag[2];
            #pragma unroll
            for (int j = 0; j < 4; ++j)
                bfrag[j] = *(const bf16x8*)((const char*)Bs + (wn * 64 + j * 16 + l16) * 128 + slot);
            #pragma unroll
            for (int i = 0; i < 2; ++i)
                afrag[i] = *(const bf16x8*)((const char*)As + (wm * 32 + i * 16 + l16) * 128 + slot);
            #pragma unroll
            for (int i = 0; i < 2; ++i)
                #pragma unroll
                for (int j = 0; j < 4; ++j)
                    acc[i][j] = __builtin_amdgcn_mfma_f32_16x16x32_bf16(afrag[i], bfrag[j], acc[i][j], 0, 0, 0);
        }
    }

    // epilogue: +bias +pos +view_embed, scatter rows to out[b, t, :]
    #pragma unroll
    for (int j = 0; j < 4; ++j) {
        int gcol = n0 + wn * 64 + j * 16 + l16;
        float bc = bias[gcol];
        float v0 = ve[gcol];
        float v1 = ve[DEC + gcol];
        #pragma unroll
        for (int i = 0; i < 2; ++i) {
            #pragma unroll
            for (int r = 0; r < 4; ++r) {
                int rl = wm * 32 + i * 16 + q * 4 + r;
                int t = rowt[rl];
                float val = acc[i][j][r] + bc + pos[(size_t)t * DEC + gcol]
                          + (t >= TOK ? v1 : v0);
                out[(size_t)rowdst[rl] * DEC + gcol] = val;
            }
        }
    }
}

extern "C" void kernel_launch(void* const* d_in, const int* in_sizes, int n_in,
                              void* d_out, int out_size, void* d_ws, size_t ws_size,
                              hipStream_t stream) {
    (void)in_sizes; (void)n_in; (void)out_size; (void)ws_size;
    const float* x    = (const float*)d_in[0];
    const int*   mids = (const int*)d_in[1];
    const float* W    = (const float*)d_in[2];
    const float* bias = (const float*)d_in[3];
    const float* mt   = (const float*)d_in[4];
    const float* pos  = (const float*)d_in[5];
    const float* ve   = (const float*)d_in[6];
    float* out = (float*)d_out;

    // workspace: x bf16 (25.7 MB) + W bf16 (1 MB) + maps
    unsigned short* xb = (unsigned short*)d_ws;                      // B*V*ENC bf16
    unsigned short* wbm = xb + (size_t)BATCH * VIS * ENC;            // DEC*ENC bf16
    int* visids = (int*)(wbm + (size_t)DEC * ENC);                   // B*V int
    unsigned char* flags = (unsigned char*)(visids + BATCH * VIS);   // B*392 bytes

    hipLaunchKernelGGL(setup, dim3(NXB + NWB + BATCH), dim3(512), 0, stream,
                       x, W, mids, xb, wbm, visids, flags);
    hipLaunchKernelGGL(fill_masked, dim3(TOK2 * 128 / 256, BATCH), dim3(256), 0, stream,
                       flags, mt, pos, ve, out);
    hipLaunchKernelGGL(gemm_scatter, dim3(4, (BATCH * VIS) / 64), dim3(256), 0, stream,
                       xb, wbm, bias, pos, ve, visids, out);
}